// Round 7
// baseline (645.717 us; speedup 1.0000x reference)
//
#include <hip/hip_runtime.h>
#include <math.h>

#define N_NODES 100000
#define N_EDGES 1600000
#define HID 128
#define OUTD 47

#define NPB 128                       // nodes per fine bucket
#define NB 782                        // ceil(100000/128)
#define BCAP 2560                     // record capacity per fine bucket
#define CHUNK 2048                    // edges per phase-A block
#define NCHB 782                      // phase-A binning blocks
#define CWB 64                        // convw blocks appended to binA grid

typedef short bf16x8 __attribute__((ext_vector_type(8)));
typedef float f32x4 __attribute__((ext_vector_type(4)));

__device__ inline unsigned short f2bf(float x) {
    union { float f; unsigned int u; } v; v.f = x;
    unsigned int r = v.u + 0x7fffu + ((v.u >> 16) & 1u);   // RNE
    return (unsigned short)(r >> 16);
}
__device__ inline float bf_lo(unsigned int u) { return __uint_as_float(u << 16); }
__device__ inline float bf_hi(unsigned int u) { return __uint_as_float(u & 0xffff0000u); }

// src-chunk for gather locality in binB sort (kept from R4)
__device__ inline unsigned int src_chunk(unsigned int s) {
    return (s * 42950u) >> 28;   // == s / 6250 for s < 100000
}

// ---------------- Phase A: bin edges by dst fine-bucket + (appended blocks) weight convert ----------------

__global__ __launch_bounds__(256) void binA_k(
    const int* __restrict__ src, const int* __restrict__ dst,
    int* __restrict__ gcur, unsigned int* __restrict__ binned,
    const float* __restrict__ W0, const float* __restrict__ W1, const float* __restrict__ W2,
    unsigned short* __restrict__ Wt0, unsigned short* __restrict__ Wt1,
    unsigned short* __restrict__ Wt2)
{
    __shared__ unsigned int sortedL[CHUNK];
    __shared__ unsigned short bucketOf[CHUNK];
    __shared__ int cntL[NB];
    __shared__ int excL[NB];
    __shared__ int curL[NB];
    __shared__ int gposL[NB];
    __shared__ int partial[256];

    int t = threadIdx.x;

    if (blockIdx.x >= NCHB) {
        int i = (blockIdx.x - NCHB) * 256 + t;
        if (i < 16384) {
            int n = i >> 7, k = i & 127;
            Wt0[i] = f2bf(W0[k * 128 + n]);
            Wt1[i] = f2bf(W1[k * 128 + n]);
        }
        if (i < 48 * 128) {
            int n = i >> 7, k = i & 127;
            Wt2[i] = (n < OUTD) ? f2bf(W2[k * OUTD + n]) : (unsigned short)0;
        }
        return;
    }

    int e0 = blockIdx.x * CHUNK;

    for (int i = t; i < NB; i += 256) cntL[i] = 0;
    __syncthreads();

    for (int i = t; i < CHUNK; i += 256) {
        int e = e0 + i;
        if (e < N_EDGES) atomicAdd(&cntL[dst[e] >> 7], 1);
    }
    __syncthreads();

    int b4 = t * 4;
    int c0 = (b4 + 0 < NB) ? cntL[b4 + 0] : 0;
    int c1 = (b4 + 1 < NB) ? cntL[b4 + 1] : 0;
    int c2 = (b4 + 2 < NB) ? cntL[b4 + 2] : 0;
    int c3 = (b4 + 3 < NB) ? cntL[b4 + 3] : 0;
    int lsum = c0 + c1 + c2 + c3;
    partial[t] = lsum;
    __syncthreads();
    for (int off = 1; off < 256; off <<= 1) {
        int x = (t >= off) ? partial[t - off] : 0;
        __syncthreads();
        partial[t] += x;
        __syncthreads();
    }
    int pbase = partial[t] - lsum;
    if (b4 + 0 < NB) { excL[b4 + 0] = pbase;                curL[b4 + 0] = pbase; }
    if (b4 + 1 < NB) { excL[b4 + 1] = pbase + c0;           curL[b4 + 1] = pbase + c0; }
    if (b4 + 2 < NB) { excL[b4 + 2] = pbase + c0 + c1;      curL[b4 + 2] = pbase + c0 + c1; }
    if (b4 + 3 < NB) { excL[b4 + 3] = pbase + c0 + c1 + c2; curL[b4 + 3] = pbase + c0 + c1 + c2; }
    __syncthreads();

    int tot = partial[255];

    for (int i = t; i < CHUNK; i += 256) {
        int e = e0 + i;
        if (e < N_EDGES) {
            int d = dst[e];
            int s = src[e];
            int bkt = d >> 7;
            int pos = atomicAdd(&curL[bkt], 1);
            sortedL[pos] = ((unsigned int)s << 7) | (unsigned int)(d & 127);
            bucketOf[pos] = (unsigned short)bkt;
        }
    }
    __syncthreads();

    for (int b = t; b < NB; b += 256) {
        int c = cntL[b];
        gposL[b] = c ? atomicAdd(&gcur[b], c) : 0;
    }
    __syncthreads();

    for (int i = t; i < tot; i += 256) {
        unsigned int r = sortedL[i];
        int bkt = bucketOf[i];
        binned[(size_t)bkt * BCAP + gposL[bkt] + (i - excL[bkt])] = r;
    }
}

// ---------------- Phase B: per-fine-bucket CSR finalize into fixed regions ----------------

__global__ __launch_bounds__(256) void binB_k(
    const unsigned int* __restrict__ binned, const int* __restrict__ gcur,
    int2* __restrict__ rowse, float* __restrict__ dinv, int* __restrict__ colv)
{
    __shared__ unsigned int recL[BCAP];
    __shared__ int colL[BCAP];
    __shared__ int hist[2048];
    __shared__ int partial[256];

    int b = blockIdx.x, t = threadIdx.x;
    int cnt = gcur[b];
    int base = b * BCAP;
    const unsigned int* rp = binned + (size_t)b * BCAP;

    for (int i = t; i < 2048; i += 256) hist[i] = 0;
    __syncthreads();

    for (int i = t; i < cnt; i += 256) {
        unsigned int r = rp[i];
        recL[i] = r;
        unsigned int key = ((r & 127u) << 4) | src_chunk(r >> 7);
        atomicAdd(&hist[key], 1);
    }
    __syncthreads();

    int base8 = t * 8;
    int v[8], lsum = 0;
#pragma unroll
    for (int j = 0; j < 8; j++) { v[j] = hist[base8 + j]; lsum += v[j]; }
    partial[t] = lsum;
    __syncthreads();
    for (int off = 1; off < 256; off <<= 1) {
        int x = (t >= off) ? partial[t - off] : 0;
        __syncthreads();
        partial[t] += x;
        __syncthreads();
    }
    int run = partial[t] - lsum;
#pragma unroll
    for (int j = 0; j < 8; j++) { hist[base8 + j] = run; run += v[j]; }
    __syncthreads();

    if (t < NPB) {
        int node = b * NPB + t;
        if (node < N_NODES) {
            int start = hist[t << 4];
            int end = (t < NPB - 1) ? hist[(t + 1) << 4] : cnt;
            rowse[node] = make_int2(base + start, base + end);
            dinv[node] = rsqrtf((float)(end - start + 1));   // +1 self-loop
        }
    }
    __syncthreads();

    for (int i = t; i < cnt; i += 256) {
        unsigned int r = recL[i];
        unsigned int key = ((r & 127u) << 4) | src_chunk(r >> 7);
        int pos = atomicAdd(&hist[key], 1);
        colL[pos] = (int)(r >> 7);
    }
    __syncthreads();
    for (int i = t; i < cnt; i += 256) colv[base + i] = colL[i];
}

// ---------------- MFMA GEMM: A (row-major fp32 or tiled bf16) @ Wt -> tiled bf16 out ----------------
// H tiled layout: [tile][node][8 uints], tile = 16 channels, uint = 2 bf16 channels.

template <int ABF16, int MODE, int NT>
__global__ __launch_bounds__(256) void gemm_k(
    const void* __restrict__ Ap, const unsigned short* __restrict__ Wt,
    const float* __restrict__ bnSum, const float* __restrict__ bnSq,
    const float* __restrict__ gam, const float* __restrict__ bet,
    const float* __restrict__ dinv, unsigned short* __restrict__ Outp,
    int ncols)
{
    __shared__ unsigned short WtL[NT * 16][136];
    __shared__ float sS[128], sT[128];

    int t = threadIdx.x;
    if (MODE) {
        if (t < 128) {
            float mean = bnSum[t] * (1.0f / N_NODES);
            float var = bnSq[t] * (1.0f / N_NODES) - mean * mean;
            float inv = rsqrtf(var + 1e-5f);
            float s = gam[t] * inv;
            sS[t] = s;
            sT[t] = bet[t] - mean * s;
        }
    }

    const int TOT = NT * 16 * 128;
    for (int e = t * 8; e < TOT; e += 256 * 8) {
        int n = e >> 7, k = e & 127;
        uint4 v = *(const uint4*)(Wt + e);
        *(uint4*)&WtL[n][k] = v;
    }
    __syncthreads();

    int wave = t >> 6, lane = t & 63;
    int quad = lane >> 4, m16 = lane & 15;
    int rbase = blockIdx.x * 128 + wave * 32;

    f32x4 acc[2][NT];
#pragma unroll
    for (int rt = 0; rt < 2; rt++)
#pragma unroll
        for (int ct = 0; ct < NT; ct++) acc[rt][ct] = (f32x4){0.f, 0.f, 0.f, 0.f};

#pragma unroll
    for (int kc = 0; kc < 4; kc++) {
        int kb = kc * 32 + quad * 8;
        bf16x8 afrag[2];
#pragma unroll
        for (int rt = 0; rt < 2; rt++) {
            int row = rbase + rt * 16 + m16;
            bool rv = (row < N_NODES);
            if (ABF16) {
                // tiled bf16: channels kb..kb+7 live in tile kb>>4, uint offset (kb&8)?4:0
                uint4 v = make_uint4(0, 0, 0, 0);
                if (rv) {
                    const unsigned int* hp = (const unsigned int*)Ap
                        + ((size_t)(kb >> 4) * N_NODES + row) * 8 + ((kb & 8) ? 4 : 0);
                    v = *(const uint4*)hp;
                }
                if (MODE) {
                    unsigned int uu[4] = {v.x, v.y, v.z, v.w};
                    unsigned short* fp = (unsigned short*)&afrag[rt];
#pragma unroll
                    for (int i = 0; i < 4; i++) {
                        int k0 = kb + 2 * i;
                        float lo = fmaxf(bf_lo(uu[i]) * sS[k0] + sT[k0], 0.f);
                        float hi = fmaxf(bf_hi(uu[i]) * sS[k0 + 1] + sT[k0 + 1], 0.f);
                        fp[2 * i] = f2bf(lo);
                        fp[2 * i + 1] = f2bf(hi);
                    }
                } else {
                    afrag[rt] = *(bf16x8*)&v;
                }
            } else {
                const float* ap = (const float*)Ap + (size_t)row * 128 + kb;
                float4 f0 = make_float4(0.f, 0.f, 0.f, 0.f), f1 = f0;
                if (rv) { f0 = *(const float4*)ap; f1 = *(const float4*)(ap + 4); }
                unsigned short* fp = (unsigned short*)&afrag[rt];
                fp[0] = f2bf(f0.x); fp[1] = f2bf(f0.y); fp[2] = f2bf(f0.z); fp[3] = f2bf(f0.w);
                fp[4] = f2bf(f1.x); fp[5] = f2bf(f1.y); fp[6] = f2bf(f1.z); fp[7] = f2bf(f1.w);
            }
        }
#pragma unroll
        for (int ct = 0; ct < NT; ct++) {
            bf16x8 bfrag = *(bf16x8*)&WtL[ct * 16 + m16][kb];
#pragma unroll
            for (int rt = 0; rt < 2; rt++)
                acc[rt][ct] = __builtin_amdgcn_mfma_f32_16x16x32_bf16(
                    afrag[rt], bfrag, acc[rt][ct], 0, 0, 0);
        }
    }

    // epilogue: dinv prescale, write tiled bf16 (tile = ct, ushort index m16)
#pragma unroll
    for (int rt = 0; rt < 2; rt++)
#pragma unroll
        for (int r = 0; r < 4; r++) {
            int row = rbase + rt * 16 + quad * 4 + r;
            if (row < N_NODES) {
                float d = dinv[row];
#pragma unroll
                for (int ct = 0; ct < NT; ct++) {
                    int c = ct * 16 + m16;
                    if (c < ncols) {
                        float val = acc[rt][ct][r] * d;
                        Outp[((size_t)ct * N_NODES + row) * 16 + m16] = f2bf(val);
                    }
                }
            }
        }
}

// ---------------- Aggregation: XCD-affine tile (blockIdx%8), 8 nodes/wave, lane=(oct,e) ----------------
// H/out layout: [8][N][8 uints]; tile = 16 channels.

__global__ __launch_bounds__(256) void agg_k(
    const unsigned int* __restrict__ H, const int2* __restrict__ rowse,
    const int* __restrict__ colv, const float* __restrict__ dinv,
    const float* __restrict__ bias, unsigned int* __restrict__ out)
{
    int T = blockIdx.x & 7;                         // XCD-affine tile
    int lane = threadIdx.x & 63;
    int oct = lane >> 3, e = lane & 7;
    int node = (blockIdx.x >> 3) * 32 + (threadIdx.x >> 6) * 8 + oct;   // 3125*32 == N exactly
    const unsigned int* Hs = H + (size_t)T * (N_NODES * 8);

    int2 se = rowse[node];
    int rp = se.x, d = se.y - se.x;

    unsigned int u = Hs[(size_t)node * 8 + e];      // self (prescaled)
    float a0 = bf_lo(u), a1 = bf_hi(u);

    int j = 0;
    for (; j + 3 < d; j += 4) {
        int s0 = __builtin_nontemporal_load(colv + rp + j);
        int s1 = __builtin_nontemporal_load(colv + rp + j + 1);
        int s2 = __builtin_nontemporal_load(colv + rp + j + 2);
        int s3 = __builtin_nontemporal_load(colv + rp + j + 3);
        unsigned int u0 = Hs[(size_t)s0 * 8 + e];
        unsigned int u1 = Hs[(size_t)s1 * 8 + e];
        unsigned int u2 = Hs[(size_t)s2 * 8 + e];
        unsigned int u3 = Hs[(size_t)s3 * 8 + e];
        a0 += bf_lo(u0) + bf_lo(u1) + bf_lo(u2) + bf_lo(u3);
        a1 += bf_hi(u0) + bf_hi(u1) + bf_hi(u2) + bf_hi(u3);
    }
    for (; j < d; j++) {
        int s0 = __builtin_nontemporal_load(colv + rp + j);
        unsigned int u0 = Hs[(size_t)s0 * 8 + e];
        a0 += bf_lo(u0);
        a1 += bf_hi(u0);
    }

    float dv = dinv[node];
    float2 b = ((const float2*)bias)[T * 8 + e];
    unsigned int r = (unsigned int)f2bf(a0 * dv + b.x)
                   | ((unsigned int)f2bf(a1 * dv + b.y) << 16);
    out[(size_t)T * (N_NODES * 8) + (size_t)node * 8 + e] = r;
}

// ---------------- Final aggregation: 3 tiles x 2 node-halves on 8 XCD slots -> fp32 logits in d_out ----------------
// Hf layout: [3][N][8 uints] (48 channels, ch 47 = zero pad).

__global__ __launch_bounds__(256) void agg_out_k(
    const unsigned int* __restrict__ H, const int2* __restrict__ rowse,
    const int* __restrict__ colv, const float* __restrict__ dinv,
    const float* __restrict__ b2, float* __restrict__ out)
{
    int q = blockIdx.x & 7;
    if (q >= 6) return;
    int T = q % 3, half = q / 3;
    int g = blockIdx.x >> 3;
    if (half == 1 && g >= 1562) return;             // half0: 1563*32=50016, half1: 1562*32=49984
    int lane = threadIdx.x & 63;
    int oct = lane >> 3, e = lane & 7;
    int node = half * 50016 + g * 32 + (threadIdx.x >> 6) * 8 + oct;
    const unsigned int* Hs = H + (size_t)T * (N_NODES * 8);

    int2 se = rowse[node];
    int rp = se.x, d = se.y - se.x;

    unsigned int u = Hs[(size_t)node * 8 + e];      // self (prescaled)
    float a0 = bf_lo(u), a1 = bf_hi(u);

    int j = 0;
    for (; j + 3 < d; j += 4) {
        int s0 = __builtin_nontemporal_load(colv + rp + j);
        int s1 = __builtin_nontemporal_load(colv + rp + j + 1);
        int s2 = __builtin_nontemporal_load(colv + rp + j + 2);
        int s3 = __builtin_nontemporal_load(colv + rp + j + 3);
        unsigned int u0 = Hs[(size_t)s0 * 8 + e];
        unsigned int u1 = Hs[(size_t)s1 * 8 + e];
        unsigned int u2 = Hs[(size_t)s2 * 8 + e];
        unsigned int u3 = Hs[(size_t)s3 * 8 + e];
        a0 += bf_lo(u0) + bf_lo(u1) + bf_lo(u2) + bf_lo(u3);
        a1 += bf_hi(u0) + bf_hi(u1) + bf_hi(u2) + bf_hi(u3);
    }
    for (; j < d; j++) {
        int s0 = __builtin_nontemporal_load(colv + rp + j);
        unsigned int u0 = Hs[(size_t)s0 * 8 + e];
        a0 += bf_lo(u0);
        a1 += bf_hi(u0);
    }

    float dv = dinv[node];
    int ch = 16 * T + 2 * e;                        // ch <= 46 always
    float* op = out + (size_t)node * OUTD;
    op[ch] = a0 * dv + b2[ch];
    if (ch + 1 < OUTD) op[ch + 1] = a1 * dv + b2[ch + 1];
}

// ---------------- log_softmax in-place on d_out: 2 nodes per wave, 32 lanes/node ----------------

__global__ __launch_bounds__(256) void lsm_k(float* __restrict__ out)
{
    int lane = threadIdx.x & 63;
    int sub = lane >> 5, cp = lane & 31;
    int node = (blockIdx.x * 4 + (threadIdx.x >> 6)) * 2 + sub;   // 12500*8 == N exactly
    int ch = cp * 2;
    float* op = out + (size_t)node * OUTD;
    float v0 = (ch < OUTD) ? op[ch] : -INFINITY;
    float v1 = (ch + 1 < OUTD) ? op[ch + 1] : -INFINITY;
    float m = fmaxf(v0, v1);
    for (int off = 1; off < 32; off <<= 1) m = fmaxf(m, __shfl_xor(m, off));
    float s = ((ch < OUTD) ? __expf(v0 - m) : 0.f)
            + ((ch + 1 < OUTD) ? __expf(v1 - m) : 0.f);
    for (int off = 1; off < 32; off <<= 1) s += __shfl_xor(s, off);
    float ls = m + logf(s);
    if (ch < OUTD) op[ch] = v0 - ls;
    if (ch + 1 < OUTD) op[ch + 1] = v1 - ls;
}

// ---------------- BatchNorm stats over tiled H ----------------

__global__ __launch_bounds__(256) void bnstats_k(const unsigned int* __restrict__ H,
                                                 float* __restrict__ sum,
                                                 float* __restrict__ sq)
{
    __shared__ float2 ls[256], lq[256];
    int t = threadIdx.x;
    int tile = blockIdx.x & 7;                      // 512 blocks = 8 tiles x 64
    const unsigned int* Hp = H + (size_t)tile * (N_NODES * 8);
    float sx = 0.f, sy = 0.f, qx = 0.f, qy = 0.f;
    for (int i = (blockIdx.x >> 3) * 256 + t; i < N_NODES * 8; i += 64 * 256) {
        unsigned int u = Hp[i];
        float x = bf_lo(u), y = bf_hi(u);
        sx += x; sy += y; qx += x * x; qy += y * y;
    }
    ls[t] = make_float2(sx, sy);
    lq[t] = make_float2(qx, qy);
    __syncthreads();
    for (int off = 128; off >= 8; off >>= 1) {      // off % 8 == 0 keeps e-class aligned
        if (t < off) {
            ls[t].x += ls[t + off].x; ls[t].y += ls[t + off].y;
            lq[t].x += lq[t + off].x; lq[t].y += lq[t + off].y;
        }
        __syncthreads();
    }
    if (t < 8) {
        int c0 = tile * 16 + 2 * t;
        atomicAdd(&sum[c0],     ls[t].x);
        atomicAdd(&sum[c0 + 1], ls[t].y);
        atomicAdd(&sq[c0],      lq[t].x);
        atomicAdd(&sq[c0 + 1],  lq[t].y);
    }
}

// ---------------- launch ----------------

extern "C" void kernel_launch(void* const* d_in, const int* in_sizes, int n_in,
                              void* d_out, int out_size, void* d_ws, size_t ws_size,
                              hipStream_t stream)
{
    const float* x   = (const float*)d_in[0];
    const int*   ei  = (const int*)d_in[1];
    const float* W0  = (const float*)d_in[2];
    const float* b0  = (const float*)d_in[3];
    const float* W1  = (const float*)d_in[4];
    const float* b1  = (const float*)d_in[5];
    const float* W2  = (const float*)d_in[6];
    const float* b2  = (const float*)d_in[7];
    const float* g0  = (const float*)d_in[8];
    const float* be0 = (const float*)d_in[9];
    const float* g1  = (const float*)d_in[10];
    const float* be1 = (const float*)d_in[11];
    const int* srcv = ei;
    const int* dstv = ei + N_EDGES;

    char* w = (char*)d_ws;
    unsigned int* H0 = (unsigned int*)w;  w += (size_t)N_NODES * 128 * 2;   // tiled bf16 [8][N][8]
    unsigned int* H1 = (unsigned int*)w;  w += (size_t)N_NODES * 128 * 2;   // tiled bf16 [8][N][8]
    unsigned int* Hf = (unsigned int*)w;  w += (size_t)N_NODES * 48 * 2;    // tiled bf16 [3][N][8]
    unsigned int* binned = (unsigned int*)w; w += (size_t)NB * BCAP * 4;    // 8.0 MB
    int* colv = (int*)w;        w += (size_t)NB * BCAP * 4;                 // 8.0 MB (fixed regions)
    unsigned short* Wt0 = (unsigned short*)w; w += 16384 * 2;
    unsigned short* Wt1 = (unsigned short*)w; w += 16384 * 2;
    unsigned short* Wt2 = (unsigned short*)w; w += 48 * 128 * 2;
    int2* rowse = (int2*)w;     w += (size_t)N_NODES * 8;
    float* dinv = (float*)w;    w += (size_t)N_NODES * 4;
    // single-memset region: gcur (784 ints) + bnS0,bnQ0,bnS1,bnQ1 (512 floats)
    int* gcur = (int*)w;        w += 784 * 4;
    float* bnS0 = (float*)w;    w += 128 * 4;
    float* bnQ0 = (float*)w;    w += 128 * 4;
    float* bnS1 = (float*)w;    w += 128 * 4;
    float* bnQ1 = (float*)w;    w += 128 * 4;

    int gb = (N_NODES + 127) / 128;       // 782 (gemm blocks)
    int agb = 3125 * 8;                   // agg_k: 3125 node-groups x 8 tiles = 25000
    int aob = 1563 * 8;                   // agg_out: max groups x 8 q-slots
    int lsb = 12500;                      // lsm: 8 nodes/block

    hipMemsetAsync(gcur, 0, (784 + 512) * 4, stream);

    binA_k<<<NCHB + CWB, 256, 0, stream>>>(srcv, dstv, gcur, binned,
                                           W0, W1, W2, Wt0, Wt1, Wt2);
    binB_k<<<NB, 256, 0, stream>>>(binned, gcur, rowse, dinv, colv);

    // Layer 0: x fp32 -> H0 tiled bf16 (dinv-prescaled)
    gemm_k<0, 0, 8><<<gb, 256, 0, stream>>>(x, Wt0, nullptr, nullptr, nullptr, nullptr,
                                            dinv, (unsigned short*)H0, 128);
    agg_k<<<agb, 256, 0, stream>>>(H0, rowse, colv, dinv, b0, H1);
    bnstats_k<<<512, 256, 0, stream>>>(H1, bnS0, bnQ0);

    // Layer 1: BN-final+BN-apply+ReLU fused into gemm, tiled in/out
    gemm_k<1, 1, 8><<<gb, 256, 0, stream>>>(H1, Wt1, bnS0, bnQ0, g0, be0,
                                            dinv, (unsigned short*)H0, 128);
    agg_k<<<agb, 256, 0, stream>>>(H0, rowse, colv, dinv, b1, H1);
    bnstats_k<<<512, 256, 0, stream>>>(H1, bnS1, bnQ1);

    // Layer 2: 48-col (ch47 zero) tiled bf16 -> fp32 logits in d_out -> in-place log_softmax
    gemm_k<1, 1, 3><<<gb, 256, 0, stream>>>(H1, Wt2, bnS1, bnQ1, g1, be1,
                                            dinv, (unsigned short*)Hf, 48);
    agg_out_k<<<aob, 256, 0, stream>>>(Hf, rowse, colv, dinv, b2, (float*)d_out);
    lsm_k<<<lsb, 256, 0, stream>>>((float*)d_out);
}

// Round 8
// 476.385 us; speedup vs baseline: 1.3555x; 1.3555x over previous
//
#include <hip/hip_runtime.h>
#include <math.h>

#define N_NODES 100000
#define N_EDGES 1600000
#define HID 128
#define OUTD 47
#define OSTR 48

#define NPB 128                       // nodes per fine bucket
#define NB 782                        // ceil(100000/128)
#define BCAP 2560                     // record capacity per fine bucket (mean 2046, max ~2300)
#define CHUNK 2048                    // edges per phase-A block
#define NCHB 782                      // phase-A binning blocks
#define CWB 64                        // convw blocks appended to binA grid

typedef _Float16 f16x2 __attribute__((ext_vector_type(2)));
typedef _Float16 f16x8 __attribute__((ext_vector_type(8)));
typedef float f32x4 __attribute__((ext_vector_type(4)));

__device__ inline unsigned short f2h(float x) {
    _Float16 h = (_Float16)x;
    return __builtin_bit_cast(unsigned short, h);
}
__device__ inline unsigned int pk2h(float lo, float hi) {
    f16x2 v; v.x = (_Float16)lo; v.y = (_Float16)hi;
    return __builtin_bit_cast(unsigned int, v);
}
__device__ inline float h_lo(unsigned int u) {
    f16x2 v = __builtin_bit_cast(f16x2, u);
    return (float)v.x;
}
__device__ inline float h_hi(unsigned int u) {
    f16x2 v = __builtin_bit_cast(f16x2, u);
    return (float)v.y;
}
__device__ inline unsigned int pkadd(unsigned int a, unsigned int b) {
    f16x2 x = __builtin_bit_cast(f16x2, a);
    f16x2 y = __builtin_bit_cast(f16x2, b);
    x = x + y;                          // v_pk_add_f16
    return __builtin_bit_cast(unsigned int, x);
}

// src-chunk for gather locality: 16 chunks of 6250 nodes
__device__ inline unsigned int src_chunk(unsigned int s) {
    return (s * 42950u) >> 28;   // == s / 6250 for s < 100000
}

// ---------------- Phase A: bin edges by dst fine-bucket + (appended blocks) weight convert ----------------

__global__ __launch_bounds__(256) void binA_k(
    const int* __restrict__ src, const int* __restrict__ dst,
    int* __restrict__ gcur, unsigned int* __restrict__ binned,
    const float* __restrict__ W0, const float* __restrict__ W1, const float* __restrict__ W2,
    unsigned short* __restrict__ Wt0, unsigned short* __restrict__ Wt1,
    unsigned short* __restrict__ Wt2)
{
    __shared__ unsigned int sortedL[CHUNK];
    __shared__ unsigned short bucketOf[CHUNK];
    __shared__ int cntL[NB];
    __shared__ int excL[NB];
    __shared__ int curL[NB];
    __shared__ int gposL[NB];
    __shared__ int partial[256];

    int t = threadIdx.x;

    if (blockIdx.x >= NCHB) {
        int i = (blockIdx.x - NCHB) * 256 + t;
        if (i < 16384) {
            int n = i >> 7, k = i & 127;
            Wt0[i] = f2h(W0[k * 128 + n]);
            Wt1[i] = f2h(W1[k * 128 + n]);
        }
        if (i < 48 * 128) {
            int n = i >> 7, k = i & 127;
            Wt2[i] = (n < OUTD) ? f2h(W2[k * OUTD + n]) : (unsigned short)0;
        }
        return;
    }

    int e0 = blockIdx.x * CHUNK;

    for (int i = t; i < NB; i += 256) cntL[i] = 0;
    __syncthreads();

    for (int i = t; i < CHUNK; i += 256) {
        int e = e0 + i;
        if (e < N_EDGES) atomicAdd(&cntL[dst[e] >> 7], 1);
    }
    __syncthreads();

    int b4 = t * 4;
    int c0 = (b4 + 0 < NB) ? cntL[b4 + 0] : 0;
    int c1 = (b4 + 1 < NB) ? cntL[b4 + 1] : 0;
    int c2 = (b4 + 2 < NB) ? cntL[b4 + 2] : 0;
    int c3 = (b4 + 3 < NB) ? cntL[b4 + 3] : 0;
    int lsum = c0 + c1 + c2 + c3;
    partial[t] = lsum;
    __syncthreads();
    for (int off = 1; off < 256; off <<= 1) {
        int x = (t >= off) ? partial[t - off] : 0;
        __syncthreads();
        partial[t] += x;
        __syncthreads();
    }
    int pbase = partial[t] - lsum;
    if (b4 + 0 < NB) { excL[b4 + 0] = pbase;                curL[b4 + 0] = pbase; }
    if (b4 + 1 < NB) { excL[b4 + 1] = pbase + c0;           curL[b4 + 1] = pbase + c0; }
    if (b4 + 2 < NB) { excL[b4 + 2] = pbase + c0 + c1;      curL[b4 + 2] = pbase + c0 + c1; }
    if (b4 + 3 < NB) { excL[b4 + 3] = pbase + c0 + c1 + c2; curL[b4 + 3] = pbase + c0 + c1 + c2; }
    __syncthreads();

    int tot = partial[255];

    for (int i = t; i < CHUNK; i += 256) {
        int e = e0 + i;
        if (e < N_EDGES) {
            int d = dst[e];
            int s = src[e];
            int bkt = d >> 7;
            int pos = atomicAdd(&curL[bkt], 1);
            sortedL[pos] = ((unsigned int)s << 7) | (unsigned int)(d & 127);
            bucketOf[pos] = (unsigned short)bkt;
        }
    }
    __syncthreads();

    for (int b = t; b < NB; b += 256) {
        int c = cntL[b];
        gposL[b] = c ? atomicAdd(&gcur[b], c) : 0;
    }
    __syncthreads();

    for (int i = t; i < tot; i += 256) {
        unsigned int r = sortedL[i];
        int bkt = bucketOf[i];
        binned[(size_t)bkt * BCAP + gposL[bkt] + (i - excL[bkt])] = r;
    }
}

// ---------------- Phase B: per-fine-bucket CSR finalize into fixed regions ----------------

__global__ __launch_bounds__(256) void binB_k(
    const unsigned int* __restrict__ binned, const int* __restrict__ gcur,
    int2* __restrict__ rowse, float* __restrict__ dinv, int* __restrict__ colv)
{
    __shared__ unsigned int recL[BCAP];
    __shared__ int colL[BCAP];
    __shared__ int hist[2048];
    __shared__ int partial[256];

    int b = blockIdx.x, t = threadIdx.x;
    int cnt = gcur[b];
    int base = b * BCAP;
    const unsigned int* rp = binned + (size_t)b * BCAP;

    for (int i = t; i < 2048; i += 256) hist[i] = 0;
    __syncthreads();

    for (int i = t; i < cnt; i += 256) {
        unsigned int r = rp[i];
        recL[i] = r;
        unsigned int key = ((r & 127u) << 4) | src_chunk(r >> 7);
        atomicAdd(&hist[key], 1);
    }
    __syncthreads();

    int base8 = t * 8;
    int v[8], lsum = 0;
#pragma unroll
    for (int j = 0; j < 8; j++) { v[j] = hist[base8 + j]; lsum += v[j]; }
    partial[t] = lsum;
    __syncthreads();
    for (int off = 1; off < 256; off <<= 1) {
        int x = (t >= off) ? partial[t - off] : 0;
        __syncthreads();
        partial[t] += x;
        __syncthreads();
    }
    int run = partial[t] - lsum;
#pragma unroll
    for (int j = 0; j < 8; j++) { hist[base8 + j] = run; run += v[j]; }
    __syncthreads();

    if (t < NPB) {
        int node = b * NPB + t;
        if (node < N_NODES) {
            int start = hist[t << 4];
            int end = (t < NPB - 1) ? hist[(t + 1) << 4] : cnt;
            rowse[node] = make_int2(base + start, base + end);
            dinv[node] = rsqrtf((float)(end - start + 1));   // +1 self-loop
        }
    }
    __syncthreads();

    for (int i = t; i < cnt; i += 256) {
        unsigned int r = recL[i];
        unsigned int key = ((r & 127u) << 4) | src_chunk(r >> 7);
        int pos = atomicAdd(&hist[key], 1);
        colL[pos] = (int)(r >> 7);
    }
    __syncthreads();
    for (int i = t; i < cnt; i += 256) colv[base + i] = colL[i];
}

// ---------------- MFMA GEMM (M x 128 @ 128 x N), f16, fused BN-final+BN-apply+ReLU, dinv prescale ----------------

template <int AF16, int MODE, int NT, int OF16>
__global__ __launch_bounds__(256) void gemm_k(
    const void* __restrict__ Ap, const unsigned short* __restrict__ Wt,
    const float* __restrict__ bnSum, const float* __restrict__ bnSq,
    const float* __restrict__ gam, const float* __restrict__ bet,
    const float* __restrict__ dinv, void* __restrict__ Outp,
    int ncols, int ostride)
{
    __shared__ unsigned short WtL[NT * 16][136];
    __shared__ float sS[128], sT[128];

    int t = threadIdx.x;
    if (MODE) {
        if (t < 128) {
            float mean = bnSum[t] * (1.0f / N_NODES);
            float var = bnSq[t] * (1.0f / N_NODES) - mean * mean;
            float inv = rsqrtf(var + 1e-5f);
            float s = gam[t] * inv;
            sS[t] = s;
            sT[t] = bet[t] - mean * s;
        }
    }

    const int TOT = NT * 16 * 128;
    for (int e = t * 8; e < TOT; e += 256 * 8) {
        int n = e >> 7, k = e & 127;
        uint4 v = *(const uint4*)(Wt + e);
        *(uint4*)&WtL[n][k] = v;
    }
    __syncthreads();

    int wave = t >> 6, lane = t & 63;
    int quad = lane >> 4, m16 = lane & 15;
    int rbase = blockIdx.x * 128 + wave * 32;

    f32x4 acc[2][NT];
#pragma unroll
    for (int rt = 0; rt < 2; rt++)
#pragma unroll
        for (int ct = 0; ct < NT; ct++) acc[rt][ct] = (f32x4){0.f, 0.f, 0.f, 0.f};

#pragma unroll
    for (int kc = 0; kc < 4; kc++) {
        int kb = kc * 32 + quad * 8;
        f16x8 afrag[2];
#pragma unroll
        for (int rt = 0; rt < 2; rt++) {
            int row = rbase + rt * 16 + m16;
            bool rv = (row < N_NODES);
            if (AF16) {
                uint4 v = make_uint4(0, 0, 0, 0);
                if (rv) v = *(const uint4*)((const unsigned short*)Ap + (size_t)row * 128 + kb);
                if (MODE) {
                    unsigned int uu[4] = {v.x, v.y, v.z, v.w};
                    unsigned int* fp = (unsigned int*)&afrag[rt];
#pragma unroll
                    for (int i = 0; i < 4; i++) {
                        int k0 = kb + 2 * i;
                        float lo = fmaxf(h_lo(uu[i]) * sS[k0] + sT[k0], 0.f);
                        float hi = fmaxf(h_hi(uu[i]) * sS[k0 + 1] + sT[k0 + 1], 0.f);
                        fp[i] = pk2h(lo, hi);
                    }
                } else {
                    afrag[rt] = __builtin_bit_cast(f16x8, v);
                }
            } else {
                const float* ap = (const float*)Ap + (size_t)row * 128 + kb;
                float4 f0 = make_float4(0.f, 0.f, 0.f, 0.f), f1 = f0;
                if (rv) { f0 = *(const float4*)ap; f1 = *(const float4*)(ap + 4); }
                f16x8 a;
                a.s0 = (_Float16)f0.x; a.s1 = (_Float16)f0.y;
                a.s2 = (_Float16)f0.z; a.s3 = (_Float16)f0.w;
                a.s4 = (_Float16)f1.x; a.s5 = (_Float16)f1.y;
                a.s6 = (_Float16)f1.z; a.s7 = (_Float16)f1.w;
                afrag[rt] = a;
            }
        }
#pragma unroll
        for (int ct = 0; ct < NT; ct++) {
            f16x8 bfrag = *(f16x8*)&WtL[ct * 16 + m16][kb];
#pragma unroll
            for (int rt = 0; rt < 2; rt++)
                acc[rt][ct] = __builtin_amdgcn_mfma_f32_16x16x32_f16(
                    afrag[rt], bfrag, acc[rt][ct], 0, 0, 0);
        }
    }

#pragma unroll
    for (int rt = 0; rt < 2; rt++)
#pragma unroll
        for (int r = 0; r < 4; r++) {
            int row = rbase + rt * 16 + quad * 4 + r;
            if (row < N_NODES) {
                float d = dinv[row];
#pragma unroll
                for (int ct = 0; ct < NT; ct++) {
                    int c = ct * 16 + m16;
                    if (c < ncols) {
                        float val = acc[rt][ct][r] * d;
                        if (OF16)
                            ((unsigned short*)Outp)[(size_t)row * ostride + c] = f2h(val);
                        else
                            ((float*)Outp)[(size_t)row * ostride + c] = val;
                    }
                }
            }
        }
}

// ---------------- Aggregation: one wave per dst node, quarter-wave per record, uint4/lane, pk f16 adds ----------------

__global__ __launch_bounds__(256) void agg_k(
    const unsigned int* __restrict__ H, const int2* __restrict__ rowse,
    const int* __restrict__ colv, const float* __restrict__ dinv,
    const float* __restrict__ bias, unsigned int* __restrict__ out)
{
    int gw = (blockIdx.x * 256 + threadIdx.x) >> 6;
    int lane = threadIdx.x & 63;
    if (gw >= N_NODES) return;
    int q = lane >> 4;             // quarter id: records 4t+q
    int c = lane & 15;             // uint4 index within row (channels 8c..8c+7)
    int2 se = rowse[gw];
    int rp = se.x, re = se.y;
    const uint4* H4 = (const uint4*)H;   // row = 16 uint4 (256 B)

    unsigned int a0 = 0, a1 = 0, a2 = 0, a3 = 0;   // packed f16x2 accumulators
    if (q == 0) {                  // self-loop (prescaled row)
        uint4 u = H4[(size_t)gw * 16 + c];
        a0 = u.x; a1 = u.y; a2 = u.z; a3 = u.w;
    }

    for (int j0 = rp; j0 < re; j0 += 64) {
        int idx = (j0 + lane < re) ? __builtin_nontemporal_load(colv + j0 + lane) : 0;
        int n = min(64, re - j0);
        int nq = n >> 2;           // complete groups of 4 records
        int t4 = 0;
        for (; t4 + 1 < nq; t4 += 2) {
            int sa = __shfl(idx, 4 * t4 + q);
            int sb = __shfl(idx, 4 * t4 + 4 + q);
            uint4 ua = H4[(size_t)sa * 16 + c];
            uint4 ub = H4[(size_t)sb * 16 + c];
            a0 = pkadd(pkadd(a0, ua.x), ub.x);
            a1 = pkadd(pkadd(a1, ua.y), ub.y);
            a2 = pkadd(pkadd(a2, ua.z), ub.z);
            a3 = pkadd(pkadd(a3, ua.w), ub.w);
        }
        if (t4 < nq) {
            int sa = __shfl(idx, 4 * t4 + q);
            uint4 ua = H4[(size_t)sa * 16 + c];
            a0 = pkadd(a0, ua.x);
            a1 = pkadd(a1, ua.y);
            a2 = pkadd(a2, ua.z);
            a3 = pkadd(a3, ua.w);
        }
        int rem = n & 3;           // tail records: quarters 0..rem-1
        if (rem) {
            int sa = __shfl(idx, (n - rem) + q);
            if (q < rem) {
                uint4 ua = H4[(size_t)sa * 16 + c];
                a0 = pkadd(a0, ua.x);
                a1 = pkadd(a1, ua.y);
                a2 = pkadd(a2, ua.z);
                a3 = pkadd(a3, ua.w);
            }
        }
    }

    // combine the four quarter accumulators (packed adds)
    a0 = pkadd(a0, (unsigned int)__shfl_xor((int)a0, 16));
    a0 = pkadd(a0, (unsigned int)__shfl_xor((int)a0, 32));
    a1 = pkadd(a1, (unsigned int)__shfl_xor((int)a1, 16));
    a1 = pkadd(a1, (unsigned int)__shfl_xor((int)a1, 32));
    a2 = pkadd(a2, (unsigned int)__shfl_xor((int)a2, 16));
    a2 = pkadd(a2, (unsigned int)__shfl_xor((int)a2, 32));
    a3 = pkadd(a3, (unsigned int)__shfl_xor((int)a3, 16));
    a3 = pkadd(a3, (unsigned int)__shfl_xor((int)a3, 32));

    if (q == 0) {
        float d = dinv[gw];
        float4 ba = ((const float4*)bias)[2 * c];
        float4 bb = ((const float4*)bias)[2 * c + 1];
        uint4 r;
        r.x = pk2h(h_lo(a0) * d + ba.x, h_hi(a0) * d + ba.y);
        r.y = pk2h(h_lo(a1) * d + ba.z, h_hi(a1) * d + ba.w);
        r.z = pk2h(h_lo(a2) * d + bb.x, h_hi(a2) * d + bb.y);
        r.w = pk2h(h_lo(a3) * d + bb.z, h_hi(a3) * d + bb.w);
        ((uint4*)out)[(size_t)gw * 16 + c] = r;
    }
}

// ---------------- Final aggregation (f16 48-stride rows), quarter-wave + log_softmax ----------------

__global__ __launch_bounds__(256) void agg_out_k(
    const unsigned int* __restrict__ H, const int2* __restrict__ rowse,
    const int* __restrict__ colv, const float* __restrict__ dinv,
    const float* __restrict__ b2, float* __restrict__ out)
{
    int gw = (blockIdx.x * 256 + threadIdx.x) >> 6;
    int lane = threadIdx.x & 63;
    if (gw >= N_NODES) return;
    int q = lane >> 4;
    int c = lane & 15;
    bool ld = c < 12;              // 12 uint2 = 48 f16 per row
    int2 se = rowse[gw];
    int rp = se.x, re = se.y;
    const uint2* H2 = (const uint2*)H;   // row = 12 uint2 (96 B)

    unsigned int a0 = 0, a1 = 0;   // packed f16x2 accumulators (4 channels)
    if (q == 0 && ld) {
        uint2 u = H2[(size_t)gw * 12 + c];   // self (prescaled)
        a0 = u.x; a1 = u.y;
    }

    for (int j0 = rp; j0 < re; j0 += 64) {
        int idx = (j0 + lane < re) ? __builtin_nontemporal_load(colv + j0 + lane) : 0;
        int n = min(64, re - j0);
        int nq = n >> 2;
        int t4 = 0;
        for (; t4 + 1 < nq; t4 += 2) {
            int sa = __shfl(idx, 4 * t4 + q);
            int sb = __shfl(idx, 4 * t4 + 4 + q);
            if (ld) {
                uint2 ua = H2[(size_t)sa * 12 + c];
                uint2 ub = H2[(size_t)sb * 12 + c];
                a0 = pkadd(pkadd(a0, ua.x), ub.x);
                a1 = pkadd(pkadd(a1, ua.y), ub.y);
            }
        }
        if (t4 < nq) {
            int sa = __shfl(idx, 4 * t4 + q);
            if (ld) {
                uint2 ua = H2[(size_t)sa * 12 + c];
                a0 = pkadd(a0, ua.x);
                a1 = pkadd(a1, ua.y);
            }
        }
        int rem = n & 3;
        if (rem) {
            int sa = __shfl(idx, (n - rem) + q);
            if (q < rem && ld) {
                uint2 ua = H2[(size_t)sa * 12 + c];
                a0 = pkadd(a0, ua.x);
                a1 = pkadd(a1, ua.y);
            }
        }
    }

    a0 = pkadd(a0, (unsigned int)__shfl_xor((int)a0, 16));
    a0 = pkadd(a0, (unsigned int)__shfl_xor((int)a0, 32));
    a1 = pkadd(a1, (unsigned int)__shfl_xor((int)a1, 16));
    a1 = pkadd(a1, (unsigned int)__shfl_xor((int)a1, 32));

    float d = dinv[gw];
    int ch = c * 4;
    float v0 = -INFINITY, v1 = -INFINITY, v2 = -INFINITY, v3 = -INFINITY;
    if (ld) {
        v0 = h_lo(a0) * d + b2[ch];
        v1 = h_hi(a0) * d + b2[ch + 1];
        v2 = h_lo(a1) * d + b2[ch + 2];
        if (ch + 3 < OUTD) v3 = h_hi(a1) * d + b2[ch + 3];
    }
    float m = fmaxf(fmaxf(v0, v1), fmaxf(v2, v3));
    m = fmaxf(m, __shfl_xor(m, 1));
    m = fmaxf(m, __shfl_xor(m, 2));
    m = fmaxf(m, __shfl_xor(m, 4));
    m = fmaxf(m, __shfl_xor(m, 8));
    float e = 0.f;
    if (ld) {
        e = __expf(v0 - m) + __expf(v1 - m) + __expf(v2 - m);
        if (ch + 3 < OUTD) e += __expf(v3 - m);
    }
    float sum = e;
    sum += __shfl_xor(sum, 1);
    sum += __shfl_xor(sum, 2);
    sum += __shfl_xor(sum, 4);
    sum += __shfl_xor(sum, 8);
    float ls = logf(sum);
    if (q == 0 && ld) {
        float* op = out + (size_t)gw * OUTD + ch;
        op[0] = v0 - m - ls;
        op[1] = v1 - m - ls;
        op[2] = v2 - m - ls;
        if (ch + 3 < OUTD) op[3] = v3 - m - ls;
    }
}

// ---------------- BatchNorm stats (f16 input) ----------------

__global__ __launch_bounds__(256) void bnstats_k(const unsigned int* __restrict__ H,
                                                 float* __restrict__ sum,
                                                 float* __restrict__ sq)
{
    __shared__ float2 ls[256], lq[256];
    int t = threadIdx.x;
    int idx = blockIdx.x * 256 + t;
    int stride = gridDim.x * 256;
    float sx = 0.f, sy = 0.f, qx = 0.f, qy = 0.f;
    for (; idx < N_NODES * 64; idx += stride) {
        unsigned int u = H[idx];
        float x = h_lo(u), y = h_hi(u);
        sx += x; sy += y; qx += x * x; qy += y * y;
    }
    ls[t] = make_float2(sx, sy);
    lq[t] = make_float2(qx, qy);
    __syncthreads();
    if (t < 64) {
        float2 a = ls[t], b = ls[t + 64], c = ls[t + 128], d = ls[t + 192];
        float2 e = lq[t], f = lq[t + 64], g = lq[t + 128], h = lq[t + 192];
        int c0 = t * 2;
        atomicAdd(&sum[c0],     a.x + b.x + c.x + d.x);
        atomicAdd(&sum[c0 + 1], a.y + b.y + c.y + d.y);
        atomicAdd(&sq[c0],      e.x + f.x + g.x + h.x);
        atomicAdd(&sq[c0 + 1],  e.y + f.y + g.y + h.y);
    }
}

// ---------------- launch ----------------

extern "C" void kernel_launch(void* const* d_in, const int* in_sizes, int n_in,
                              void* d_out, int out_size, void* d_ws, size_t ws_size,
                              hipStream_t stream)
{
    const float* x   = (const float*)d_in[0];
    const int*   ei  = (const int*)d_in[1];
    const float* W0  = (const float*)d_in[2];
    const float* b0  = (const float*)d_in[3];
    const float* W1  = (const float*)d_in[4];
    const float* b1  = (const float*)d_in[5];
    const float* W2  = (const float*)d_in[6];
    const float* b2  = (const float*)d_in[7];
    const float* g0  = (const float*)d_in[8];
    const float* be0 = (const float*)d_in[9];
    const float* g1  = (const float*)d_in[10];
    const float* be1 = (const float*)d_in[11];
    const int* srcv = ei;
    const int* dstv = ei + N_EDGES;

    char* w = (char*)d_ws;
    unsigned int* H0 = (unsigned int*)w;  w += (size_t)N_NODES * 128 * 2;   // f16 [N][128]
    unsigned int* H1 = (unsigned int*)w;  w += (size_t)N_NODES * 128 * 2;   // f16 [N][128]
    unsigned int* Hf = (unsigned int*)w;  w += (size_t)N_NODES * OSTR * 2;  // f16 [N][48]
    unsigned int* binned = (unsigned int*)w; w += (size_t)NB * BCAP * 4;    // 8.0 MB
    int* colv = (int*)w;        w += (size_t)NB * BCAP * 4;                 // 8.0 MB (fixed regions)
    unsigned short* Wt0 = (unsigned short*)w; w += 16384 * 2;
    unsigned short* Wt1 = (unsigned short*)w; w += 16384 * 2;
    unsigned short* Wt2 = (unsigned short*)w; w += 48 * 128 * 2;
    int2* rowse = (int2*)w;     w += (size_t)N_NODES * 8;
    float* dinv = (float*)w;    w += (size_t)N_NODES * 4;
    // single-memset region: gcur (784 ints) + bnS0,bnQ0,bnS1,bnQ1 (512 floats)
    int* gcur = (int*)w;        w += 784 * 4;
    float* bnS0 = (float*)w;    w += 128 * 4;
    float* bnQ0 = (float*)w;    w += 128 * 4;
    float* bnS1 = (float*)w;    w += 128 * 4;
    float* bnQ1 = (float*)w;    w += 128 * 4;

    int gb = (N_NODES + 127) / 128;       // 782
    int ab = (N_NODES * 64 + 255) / 256;  // 25000

    hipMemsetAsync(gcur, 0, (784 + 512) * 4, stream);

    binA_k<<<NCHB + CWB, 256, 0, stream>>>(srcv, dstv, gcur, binned,
                                           W0, W1, W2, Wt0, Wt1, Wt2);
    binB_k<<<NB, 256, 0, stream>>>(binned, gcur, rowse, dinv, colv);

    // Layer 0: x fp32 -> H0 f16 (dinv-prescaled)
    gemm_k<0, 0, 8, 1><<<gb, 256, 0, stream>>>(x, Wt0, nullptr, nullptr, nullptr, nullptr,
                                               dinv, H0, 128, 128);
    agg_k<<<ab, 256, 0, stream>>>(H0, rowse, colv, dinv, b0, H1);
    bnstats_k<<<512, 256, 0, stream>>>(H1, bnS0, bnQ0);

    // Layer 1: BN-final+BN-apply+ReLU fused into gemm, f16 MFMA
    gemm_k<1, 1, 8, 1><<<gb, 256, 0, stream>>>(H1, Wt1, bnS0, bnQ0, g0, be0,
                                               dinv, H0, 128, 128);
    agg_k<<<ab, 256, 0, stream>>>(H0, rowse, colv, dinv, b1, H1);
    bnstats_k<<<512, 256, 0, stream>>>(H1, bnS1, bnQ1);

    // Layer 2: 47-wide out (f16, stride 48) + fused log_softmax aggregation
    gemm_k<1, 1, 3, 1><<<gb, 256, 0, stream>>>(H1, Wt2, bnS1, bnQ1, g1, be1,
                                               dinv, Hf, OUTD, OSTR);
    agg_out_k<<<ab, 256, 0, stream>>>(Hf, rowse, colv, dinv, b2, (float*)d_out);
}